// Round 1
// baseline (1022.545 us; speedup 1.0000x reference)
//
#include <hip/hip_runtime.h>
#include <hip/hip_bf16.h>

typedef __attribute__((ext_vector_type(8))) short short8;
typedef __attribute__((ext_vector_type(4))) float f32x4;

#define VOXELS 262144  // 64^3
#define F_PAD  872     // 864 + 8 ; 1744 B row stride (16-mult, 2-way bank alias only)
#define ZC_PAD 264     // 256 + 8
#define Z0_PAD 72      // 64 + 8
#define Z2_PAD 520     // 512 + 8
#define Z3_PAD 264     // 256 + 8

// ---------------- volume transpose: (C,D,H,W) -> (D,H,W,C) fp32 ----------------
__global__ void k_transpose(const float* __restrict__ v0, const float* __restrict__ v1,
                            const float* __restrict__ v2, const float* __restrict__ v3,
                            float* __restrict__ vt) {
    int b  = blockIdx.x;
    int q  = b >> 12;          // 4096 (z,y) rows per volume
    int zy = b & 4095;
    const float* src = (q == 0) ? v0 : (q == 1) ? v1 : (q == 2) ? v2 : v3;
    __shared__ float buf[32][65];
    int t = threadIdx.x;
    int x = t & 63, c0 = t >> 6;               // 4 channels per pass
    for (int cp = 0; cp < 32; cp += 4) {
        int c = c0 + cp;
        buf[c][x] = src[(size_t)c * VOXELS + (size_t)zy * 64 + x];
    }
    __syncthreads();
    int c = t & 31, xg = t >> 5;
    float* dst = vt + ((size_t)q * VOXELS + (size_t)zy * 64) * 32;
    for (int xx = xg; xx < 64; xx += 8) {
        dst[xx * 32 + c] = buf[c][xx];
    }
}

// ------------- weight pack: W[O][K] fp32 -> bf16 MFMA-B fragment order -------------
// out[((otile*KSTEPS + kstep)*64 + lane)*8 + e] = W[otile*16 + (lane&15)][kstep*32 + (lane>>4)*8 + e]
// conv_remap: logical k = s*32+c maps to source index c*27+s (conv_w is [O][C2][27])
__global__ void k_prepw(const float* __restrict__ W, __hip_bfloat16* __restrict__ wf,
                        int O, int K, int conv_remap) {
    int n = blockIdx.x * blockDim.x + threadIdx.x;
    if (n >= O * K) return;
    int e = n & 7, lane = (n >> 3) & 63;
    int rest = n >> 9;
    int ksteps = K >> 5;
    int kstep = rest % ksteps, otile = rest / ksteps;
    int o = otile * 16 + (lane & 15);
    int k = kstep * 32 + (lane >> 4) * 8 + e;
    int ksrc = conv_remap ? ((k & 31) * 27 + (k >> 5)) : k;
    wf[n] = __float2bfloat16(W[(size_t)o * K + ksrc]);
}

// ---------------- fully fused: sample -> conv -> lfc -> fc1..fc4 ----------------
template <bool CHLAST>
__global__ __launch_bounds__(1024)
void k_fused(const float* __restrict__ xin, const float* __restrict__ vt,
             const float* __restrict__ v0, const float* __restrict__ v1,
             const float* __restrict__ v2, const float* __restrict__ v3,
             const __hip_bfloat16* __restrict__ w0f, const float* __restrict__ b0,
             const __hip_bfloat16* __restrict__ w1f, const float* __restrict__ b1,
             const float* __restrict__ fc1w, const float* __restrict__ fc1b,
             const __hip_bfloat16* __restrict__ w2f, const float* __restrict__ b2,
             const __hip_bfloat16* __restrict__ w3f, const float* __restrict__ b3,
             const float* __restrict__ fc4w, const float* __restrict__ fc4b,
             float* __restrict__ out, int m) {
    __shared__ __align__(16) __hip_bfloat16 f_lds[16][F_PAD];
    __shared__ __align__(16) __hip_bfloat16 zcat[16][ZC_PAD];
    __shared__ __align__(16) __hip_bfloat16 z0l[16][Z0_PAD];
    __shared__ __align__(16) __hip_bfloat16 z2l[16][Z2_PAD];
    __shared__ __align__(16) __hip_bfloat16 z3l[16][Z3_PAD];
    __shared__ float ptl[16][3];

    const int tid  = threadIdx.x;
    const int wave = tid >> 6;
    const int lane = tid & 63;
    const int p0   = blockIdx.x * 16;

    // ================= phase 1: sampling (one wave per point) =================
    {
        const int pt = wave;
        const int p  = min(p0 + pt, m - 1);
        const float px = xin[p * 3 + 0];
        const float py = xin[p * 3 + 1];
        const float pz = xin[p * 3 + 2];
        if (lane == 0) { ptl[pt][0] = px; ptl[pt][1] = py; ptl[pt][2] = pz; }

        const int c5   = lane & 31;
        const int half = lane >> 5;

        float f_reg[27];
#pragma unroll
        for (int s = 0; s < 27; ++s) f_reg[s] = 0.f;

        const float G0 = -2.0f, G1 = -0.5f, G2 = 1.0f;

#pragma unroll 1
        for (int q = 0; q < 4; ++q) {
            const float sc = (float)(2 << q) * (1.0f / 64.0f);  // 2*2^q/64
            const float* vq;
            if (CHLAST) {
                vq = vt + (size_t)q * ((size_t)VOXELS * 32);
            } else {
                vq = (q == 0) ? v0 : (q == 1) ? v1 : (q == 2) ? v2 : v3;
            }
#pragma unroll
            for (int s = 0; s < 27; ++s) {
                const int j = s / 9, i = (s / 3) % 3, kk = s % 3;
                const float gx = (j == 0) ? G0 : (j == 1) ? G1 : G2;
                const float gy = (i == 0) ? G0 : (i == 1) ? G1 : G2;
                const float gz = (kk == 0) ? G0 : (kk == 1) ? G1 : G2;
                float ix = fminf(fmaxf((px + gx * sc + 1.f) * 31.5f, 0.f), 63.f);
                float iy = fminf(fmaxf((py + gy * sc + 1.f) * 31.5f, 0.f), 63.f);
                float iz = fminf(fmaxf((pz + gz * sc + 1.f) * 31.5f, 0.f), 63.f);
                float xf = floorf(ix), yf = floorf(iy), zf = floorf(iz);
                int x0 = (int)xf, y0 = (int)yf, z0 = (int)zf;
                float fx = ix - xf, fy = iy - yf, fz = iz - zf;
                int x1 = min(x0 + 1, 63), y1 = min(y0 + 1, 63), z1 = min(z0 + 1, 63);
                int xs = half ? x1 : x0;
                float wx = half ? fx : 1.f - fx;
                float v00, v01, v10, v11;
                if (CHLAST) {
                    const float* base = vq + c5;
                    v00 = base[((z0 * 64 + y0) * 64 + xs) << 5];
                    v01 = base[((z0 * 64 + y1) * 64 + xs) << 5];
                    v10 = base[((z1 * 64 + y0) * 64 + xs) << 5];
                    v11 = base[((z1 * 64 + y1) * 64 + xs) << 5];
                } else {
                    const float* base = vq + (size_t)c5 * VOXELS;
                    v00 = base[(z0 * 64 + y0) * 64 + xs];
                    v01 = base[(z0 * 64 + y1) * 64 + xs];
                    v10 = base[(z1 * 64 + y0) * 64 + xs];
                    v11 = base[(z1 * 64 + y1) * 64 + xs];
                }
                float a = v00 * (1.f - fz) * (1.f - fy) + v01 * (1.f - fz) * fy
                        + v10 * fz * (1.f - fy)        + v11 * fz * fy;
                f_reg[s] += wx * a;
            }
        }
#pragma unroll
        for (int s = 0; s < 27; ++s) {
            float tot = f_reg[s] + __shfl_xor(f_reg[s], 32);
            if (half == 0) f_lds[pt][s * 32 + c5] = __float2bfloat16(tot);
        }
    }
    __syncthreads();

    // ============ phase 2a: z_point = leaky(x @ fc1^T + b) -> zcat[:,0:128] ============
    {
        const int ptp = tid >> 6;
        const int ob  = tid & 63;
        const float qx = ptl[ptp][0], qy = ptl[ptp][1], qz = ptl[ptp][2];
#pragma unroll
        for (int r = 0; r < 2; ++r) {
            const int o = ob + 64 * r;
            float v = qx * fc1w[o * 3 + 0] + qy * fc1w[o * 3 + 1] + qz * fc1w[o * 3 + 2] + fc1b[o];
            v = fmaxf(v, 0.2f * v);
            zcat[ptp][o] = __float2bfloat16(v);
        }
    }

    // ============ phase 2b: conv GEMM [16x864]x[864x64] (waves 0..3) ============
    if (wave < 4) {
        f32x4 acc = {0.f, 0.f, 0.f, 0.f};
        const int row = lane & 15, g = lane >> 4;
        for (int ks = 0; ks < 27; ++ks) {
            short8 af = *(const short8*)&f_lds[row][ks * 32 + g * 8];
            short8 bf = *(const short8*)(w0f + (((size_t)wave * 27 + ks) * 64 + lane) * 8);
            acc = __builtin_amdgcn_mfma_f32_16x16x32_bf16(af, bf, acc, 0, 0, 0);
        }
        const int o = wave * 16 + row;
        const float bias = b0[o];
#pragma unroll
        for (int r = 0; r < 4; ++r)
            z0l[g * 4 + r][o] = __float2bfloat16(acc[r] + bias);
    }
    __syncthreads();

    // ============ phase 3: lfc GEMM [16x64]x[64x128] (waves 0..7) -> zcat[:,128:256] ============
    if (wave < 8) {
        f32x4 acc = {0.f, 0.f, 0.f, 0.f};
        const int row = lane & 15, g = lane >> 4;
#pragma unroll
        for (int ks = 0; ks < 2; ++ks) {
            short8 af = *(const short8*)&z0l[row][ks * 32 + g * 8];
            short8 bf = *(const short8*)(w1f + (((size_t)wave * 2 + ks) * 64 + lane) * 8);
            acc = __builtin_amdgcn_mfma_f32_16x16x32_bf16(af, bf, acc, 0, 0, 0);
        }
        const int o = wave * 16 + row;
        const float bias = b1[o];
#pragma unroll
        for (int r = 0; r < 4; ++r)
            zcat[g * 4 + r][128 + o] = __float2bfloat16(acc[r] + bias);
    }
    __syncthreads();

    // ============ phase 4: fc2 [16x256]x[256x512], leaky (16 waves x 2 tiles) ============
    {
        const int row = lane & 15, g = lane >> 4;
#pragma unroll
        for (int rt = 0; rt < 2; ++rt) {
            const int tile = wave * 2 + rt;
            f32x4 acc = {0.f, 0.f, 0.f, 0.f};
#pragma unroll
            for (int ks = 0; ks < 8; ++ks) {
                short8 af = *(const short8*)&zcat[row][ks * 32 + g * 8];
                short8 bf = *(const short8*)(w2f + (((size_t)tile * 8 + ks) * 64 + lane) * 8);
                acc = __builtin_amdgcn_mfma_f32_16x16x32_bf16(af, bf, acc, 0, 0, 0);
            }
            const int o = tile * 16 + row;
            const float bias = b2[o];
#pragma unroll
            for (int r = 0; r < 4; ++r) {
                float v = acc[r] + bias;
                v = fmaxf(v, 0.2f * v);
                z2l[g * 4 + r][o] = __float2bfloat16(v);
            }
        }
    }
    __syncthreads();

    // ============ phase 5: fc3 [16x512]x[512x256], leaky (wave = tile) ============
    {
        const int row = lane & 15, g = lane >> 4;
        f32x4 acc = {0.f, 0.f, 0.f, 0.f};
        for (int ks = 0; ks < 16; ++ks) {
            short8 af = *(const short8*)&z2l[row][ks * 32 + g * 8];
            short8 bf = *(const short8*)(w3f + (((size_t)wave * 16 + ks) * 64 + lane) * 8);
            acc = __builtin_amdgcn_mfma_f32_16x16x32_bf16(af, bf, acc, 0, 0, 0);
        }
        const int o = wave * 16 + row;
        const float bias = b3[o];
#pragma unroll
        for (int r = 0; r < 4; ++r) {
            float v = acc[r] + bias;
            v = fmaxf(v, 0.2f * v);
            z3l[g * 4 + r][o] = __float2bfloat16(v);
        }
    }
    __syncthreads();

    // ============ phase 6: fc4 [16x256]x[256x3] (waves 0..2, o = wave) ============
    if (wave < 3) {
        const int ptq = lane & 15, kg = lane >> 4;
        const int o = wave;
        float s = 0.f;
        for (int kk = 0; kk < 64; ++kk) {
            const int k = kg * 64 + kk;
            s += __bfloat162float(z3l[ptq][k]) * fc4w[o * 256 + k];
        }
        s += __shfl_xor(s, 16);
        s += __shfl_xor(s, 32);
        if (kg == 0) {
            const int pg = p0 + ptq;
            if (pg < m) out[pg * 3 + o] = s + fc4b[o];
        }
    }
}

extern "C" void kernel_launch(void* const* d_in, const int* in_sizes, int n_in,
                              void* d_out, int out_size, void* d_ws, size_t ws_size,
                              hipStream_t stream) {
    const float* x      = (const float*)d_in[1];
    const float* v0     = (const float*)d_in[2];
    const float* v1     = (const float*)d_in[3];
    const float* v2     = (const float*)d_in[4];
    const float* v3     = (const float*)d_in[5];
    const float* conv_w = (const float*)d_in[6];
    const float* conv_b = (const float*)d_in[7];
    const float* lfc_w  = (const float*)d_in[8];
    const float* lfc_b  = (const float*)d_in[9];
    const float* fc1_w  = (const float*)d_in[10];
    const float* fc1_b  = (const float*)d_in[11];
    const float* fc2_w  = (const float*)d_in[12];
    const float* fc2_b  = (const float*)d_in[13];
    const float* fc3_w  = (const float*)d_in[14];
    const float* fc3_b  = (const float*)d_in[15];
    const float* fc4_w  = (const float*)d_in[16];
    const float* fc4_b  = (const float*)d_in[17];
    float* out = (float*)d_out;
    const int m = in_sizes[1] / 3;

    char* ws = (char*)d_ws;
    size_t woff = 0;
    __hip_bfloat16* w0f = (__hip_bfloat16*)(ws + woff); woff += (size_t)55296 * 2;
    __hip_bfloat16* w1f = (__hip_bfloat16*)(ws + woff); woff += (size_t)8192 * 2;
    __hip_bfloat16* w2f = (__hip_bfloat16*)(ws + woff); woff += (size_t)131072 * 2;
    __hip_bfloat16* w3f = (__hip_bfloat16*)(ws + woff); woff += (size_t)131072 * 2;
    woff = (woff + 255) & ~(size_t)255;
    float* vt = (float*)(ws + woff);
    const size_t need = woff + (size_t)4 * VOXELS * 32 * 4;
    const bool chlast = (ws_size >= need);

    k_prepw<<<(55296 + 255) / 256, 256, 0, stream>>>(conv_w, w0f, 64, 864, 1);
    k_prepw<<<(8192 + 255) / 256, 256, 0, stream>>>(lfc_w, w1f, 128, 64, 0);
    k_prepw<<<(131072 + 255) / 256, 256, 0, stream>>>(fc2_w, w2f, 512, 256, 0);
    k_prepw<<<(131072 + 255) / 256, 256, 0, stream>>>(fc3_w, w3f, 256, 512, 0);
    if (chlast) {
        k_transpose<<<16384, 256, 0, stream>>>(v0, v1, v2, v3, vt);
    }

    const int nb = (m + 15) / 16;
    if (chlast) {
        k_fused<true><<<nb, 1024, 0, stream>>>(x, vt, v0, v1, v2, v3,
                                               w0f, conv_b, w1f, lfc_b, fc1_w, fc1_b,
                                               w2f, fc2_b, w3f, fc3_b, fc4_w, fc4_b, out, m);
    } else {
        k_fused<false><<<nb, 1024, 0, stream>>>(x, vt, v0, v1, v2, v3,
                                                w0f, conv_b, w1f, lfc_b, fc1_w, fc1_b,
                                                w2f, fc2_b, w3f, fc3_b, fc4_w, fc4_b, out, m);
    }
}

// Round 2
// 725.206 us; speedup vs baseline: 1.4100x; 1.4100x over previous
//
#include <hip/hip_runtime.h>
#include <hip/hip_bf16.h>

typedef __attribute__((ext_vector_type(8))) short short8;
typedef __attribute__((ext_vector_type(4))) float f32x4;

#define VOXELS 262144  // 64^3
#define F_PAD  872     // 864 + 8 ; 1744 B row stride (16-mult, 2-way bank alias only)
#define ZC_PAD 264     // 256 + 8
#define Z0_PAD 72      // 64 + 8
#define Z2_PAD 520     // 512 + 8
#define Z3_PAD 264     // 256 + 8

// ---------------- volume transpose: (C,D,H,W) -> (D,H,W,C) fp32 ----------------
__global__ void k_transpose(const float* __restrict__ v0, const float* __restrict__ v1,
                            const float* __restrict__ v2, const float* __restrict__ v3,
                            float* __restrict__ vt) {
    int b  = blockIdx.x;
    int q  = b >> 12;          // 4096 (z,y) rows per volume
    int zy = b & 4095;
    const float* src = (q == 0) ? v0 : (q == 1) ? v1 : (q == 2) ? v2 : v3;
    __shared__ float buf[32][65];
    int t = threadIdx.x;
    int x = t & 63, c0 = t >> 6;               // 4 channels per pass
    for (int cp = 0; cp < 32; cp += 4) {
        int c = c0 + cp;
        buf[c][x] = src[(size_t)c * VOXELS + (size_t)zy * 64 + x];
    }
    __syncthreads();
    int c = t & 31, xg = t >> 5;
    float* dst = vt + ((size_t)q * VOXELS + (size_t)zy * 64) * 32;
    for (int xx = xg; xx < 64; xx += 8) {
        dst[xx * 32 + c] = buf[c][xx];
    }
}

// ------------- weight pack: W[O][K] fp32 -> bf16 MFMA-B fragment order -------------
// out[((otile*KSTEPS + kstep)*64 + lane)*8 + e] = W[otile*16 + (lane&15)][kstep*32 + (lane>>4)*8 + e]
// conv_remap: logical k = s*32+c maps to source index c*27+s (conv_w is [O][C2][27])
__global__ void k_prepw(const float* __restrict__ W, __hip_bfloat16* __restrict__ wf,
                        int O, int K, int conv_remap) {
    int n = blockIdx.x * blockDim.x + threadIdx.x;
    if (n >= O * K) return;
    int e = n & 7, lane = (n >> 3) & 63;
    int rest = n >> 9;
    int ksteps = K >> 5;
    int kstep = rest % ksteps, otile = rest / ksteps;
    int o = otile * 16 + (lane & 15);
    int k = kstep * 32 + (lane >> 4) * 8 + e;
    int ksrc = conv_remap ? ((k & 31) * 27 + (k >> 5)) : k;
    wf[n] = __float2bfloat16(W[(size_t)o * K + ksrc]);
}

// ---------------- fully fused: sample -> conv -> lfc -> fc1..fc4 ----------------
template <bool CHLAST>
__global__ __launch_bounds__(1024)
void k_fused(const float* __restrict__ xin, const float* __restrict__ vt,
             const float* __restrict__ v0, const float* __restrict__ v1,
             const float* __restrict__ v2, const float* __restrict__ v3,
             const __hip_bfloat16* __restrict__ w0f, const float* __restrict__ b0,
             const __hip_bfloat16* __restrict__ w1f, const float* __restrict__ b1,
             const float* __restrict__ fc1w, const float* __restrict__ fc1b,
             const __hip_bfloat16* __restrict__ w2f, const float* __restrict__ b2,
             const __hip_bfloat16* __restrict__ w3f, const float* __restrict__ b3,
             const float* __restrict__ fc4w, const float* __restrict__ fc4b,
             float* __restrict__ out, int m) {
    __shared__ __align__(16) __hip_bfloat16 f_lds[16][F_PAD];
    __shared__ __align__(16) __hip_bfloat16 zcat[16][ZC_PAD];
    __shared__ __align__(16) __hip_bfloat16 z0l[16][Z0_PAD];
    __shared__ __align__(16) __hip_bfloat16 z2l[16][Z2_PAD];
    __shared__ __align__(16) __hip_bfloat16 z3l[16][Z3_PAD];
    __shared__ float ptl[16][3];

    const int tid  = threadIdx.x;
    const int wave = tid >> 6;
    const int lane = tid & 63;
    const int p0   = blockIdx.x * 16;

    // ================= phase 1: sampling (one wave per point) =================
    // s-outer (unroll 1) / q-inner (full unroll): per-s accumulator dies at the
    // LDS store, so live state = ~16 in-flight loads + temps -> fits 64 VGPRs,
    // no scratch spill (round-1 killer: f_reg[27] spilled, 1.2 GB scratch writes).
    {
        const int pt = wave;
        const int p  = min(p0 + pt, m - 1);
        const float px = xin[p * 3 + 0];
        const float py = xin[p * 3 + 1];
        const float pz = xin[p * 3 + 2];
        if (lane == 0) { ptl[pt][0] = px; ptl[pt][1] = py; ptl[pt][2] = pz; }

        const int c5   = lane & 31;
        const int half = lane >> 5;

        // (p + g*sc + 1)*31.5 = (p*31.5 + 31.5) + g*(sc*31.5)
        const float pxs = px * 31.5f + 31.5f;
        const float pys = py * 31.5f + 31.5f;
        const float pzs = pz * 31.5f + 31.5f;

#pragma unroll 1
        for (int s = 0; s < 27; ++s) {
            const int j = s / 9, i = (s / 3) % 3, kk = s % 3;
            // grid = [-2, -0.5, 1] = -2 + 1.5*idx  (no runtime-indexed array)
            const float gx = -2.0f + 1.5f * (float)j;
            const float gy = -2.0f + 1.5f * (float)i;
            const float gz = -2.0f + 1.5f * (float)kk;

            float acc = 0.f;
#pragma unroll
            for (int q = 0; q < 4; ++q) {
                const float sc31 = (float)(2 << q) * (31.5f / 64.0f);  // sc*31.5, compile-time
                float ix = fminf(fmaxf(pxs + gx * sc31, 0.f), 63.f);
                float iy = fminf(fmaxf(pys + gy * sc31, 0.f), 63.f);
                float iz = fminf(fmaxf(pzs + gz * sc31, 0.f), 63.f);
                float xf = floorf(ix), yf = floorf(iy), zf = floorf(iz);
                int x0 = (int)xf, y0 = (int)yf, z0 = (int)zf;
                float fx = ix - xf, fy = iy - yf, fz = iz - zf;
                int x1 = min(x0 + 1, 63), y1 = min(y0 + 1, 63), z1 = min(z0 + 1, 63);
                int xs = half ? x1 : x0;
                float wx = half ? fx : 1.f - fx;
                float v00, v01, v10, v11;
                if (CHLAST) {
                    const float* base = vt + (size_t)q * ((size_t)VOXELS * 32) + c5;
                    v00 = base[((z0 * 64 + y0) * 64 + xs) << 5];
                    v01 = base[((z0 * 64 + y1) * 64 + xs) << 5];
                    v10 = base[((z1 * 64 + y0) * 64 + xs) << 5];
                    v11 = base[((z1 * 64 + y1) * 64 + xs) << 5];
                } else {
                    const float* vq = (q == 0) ? v0 : (q == 1) ? v1 : (q == 2) ? v2 : v3;
                    const float* base = vq + (size_t)c5 * VOXELS;
                    v00 = base[(z0 * 64 + y0) * 64 + xs];
                    v01 = base[(z0 * 64 + y1) * 64 + xs];
                    v10 = base[(z1 * 64 + y0) * 64 + xs];
                    v11 = base[(z1 * 64 + y1) * 64 + xs];
                }
                float a = v00 * (1.f - fz) * (1.f - fy) + v01 * (1.f - fz) * fy
                        + v10 * fz * (1.f - fy)        + v11 * fz * fy;
                acc += wx * a;
            }
            float tot = acc + __shfl_xor(acc, 32);
            if (half == 0) f_lds[pt][s * 32 + c5] = __float2bfloat16(tot);
        }
    }
    __syncthreads();

    // ============ phase 2a: z_point = leaky(x @ fc1^T + b) -> zcat[:,0:128] ============
    {
        const int ptp = tid >> 6;
        const int ob  = tid & 63;
        const float qx = ptl[ptp][0], qy = ptl[ptp][1], qz = ptl[ptp][2];
#pragma unroll
        for (int r = 0; r < 2; ++r) {
            const int o = ob + 64 * r;
            float v = qx * fc1w[o * 3 + 0] + qy * fc1w[o * 3 + 1] + qz * fc1w[o * 3 + 2] + fc1b[o];
            v = fmaxf(v, 0.2f * v);
            zcat[ptp][o] = __float2bfloat16(v);
        }
    }

    // ============ phase 2b: conv GEMM [16x864]x[864x64] (waves 0..3) ============
    if (wave < 4) {
        f32x4 acc = {0.f, 0.f, 0.f, 0.f};
        const int row = lane & 15, g = lane >> 4;
        for (int ks = 0; ks < 27; ++ks) {
            short8 af = *(const short8*)&f_lds[row][ks * 32 + g * 8];
            short8 bf = *(const short8*)(w0f + (((size_t)wave * 27 + ks) * 64 + lane) * 8);
            acc = __builtin_amdgcn_mfma_f32_16x16x32_bf16(af, bf, acc, 0, 0, 0);
        }
        const int o = wave * 16 + row;
        const float bias = b0[o];
#pragma unroll
        for (int r = 0; r < 4; ++r)
            z0l[g * 4 + r][o] = __float2bfloat16(acc[r] + bias);
    }
    __syncthreads();

    // ============ phase 3: lfc GEMM [16x64]x[64x128] (waves 0..7) -> zcat[:,128:256] ============
    if (wave < 8) {
        f32x4 acc = {0.f, 0.f, 0.f, 0.f};
        const int row = lane & 15, g = lane >> 4;
#pragma unroll
        for (int ks = 0; ks < 2; ++ks) {
            short8 af = *(const short8*)&z0l[row][ks * 32 + g * 8];
            short8 bf = *(const short8*)(w1f + (((size_t)wave * 2 + ks) * 64 + lane) * 8);
            acc = __builtin_amdgcn_mfma_f32_16x16x32_bf16(af, bf, acc, 0, 0, 0);
        }
        const int o = wave * 16 + row;
        const float bias = b1[o];
#pragma unroll
        for (int r = 0; r < 4; ++r)
            zcat[g * 4 + r][128 + o] = __float2bfloat16(acc[r] + bias);
    }
    __syncthreads();

    // ============ phase 4: fc2 [16x256]x[256x512], leaky (16 waves x 2 tiles) ============
    {
        const int row = lane & 15, g = lane >> 4;
#pragma unroll
        for (int rt = 0; rt < 2; ++rt) {
            const int tile = wave * 2 + rt;
            f32x4 acc = {0.f, 0.f, 0.f, 0.f};
#pragma unroll
            for (int ks = 0; ks < 8; ++ks) {
                short8 af = *(const short8*)&zcat[row][ks * 32 + g * 8];
                short8 bf = *(const short8*)(w2f + (((size_t)tile * 8 + ks) * 64 + lane) * 8);
                acc = __builtin_amdgcn_mfma_f32_16x16x32_bf16(af, bf, acc, 0, 0, 0);
            }
            const int o = tile * 16 + row;
            const float bias = b2[o];
#pragma unroll
            for (int r = 0; r < 4; ++r) {
                float v = acc[r] + bias;
                v = fmaxf(v, 0.2f * v);
                z2l[g * 4 + r][o] = __float2bfloat16(v);
            }
        }
    }
    __syncthreads();

    // ============ phase 5: fc3 [16x512]x[512x256], leaky (wave = tile) ============
    {
        const int row = lane & 15, g = lane >> 4;
        f32x4 acc = {0.f, 0.f, 0.f, 0.f};
        for (int ks = 0; ks < 16; ++ks) {
            short8 af = *(const short8*)&z2l[row][ks * 32 + g * 8];
            short8 bf = *(const short8*)(w3f + (((size_t)wave * 16 + ks) * 64 + lane) * 8);
            acc = __builtin_amdgcn_mfma_f32_16x16x32_bf16(af, bf, acc, 0, 0, 0);
        }
        const int o = wave * 16 + row;
        const float bias = b3[o];
#pragma unroll
        for (int r = 0; r < 4; ++r) {
            float v = acc[r] + bias;
            v = fmaxf(v, 0.2f * v);
            z3l[g * 4 + r][o] = __float2bfloat16(v);
        }
    }
    __syncthreads();

    // ============ phase 6: fc4 [16x256]x[256x3] (waves 0..2, o = wave) ============
    if (wave < 3) {
        const int ptq = lane & 15, kg = lane >> 4;
        const int o = wave;
        float s = 0.f;
        for (int kk = 0; kk < 64; ++kk) {
            const int k = kg * 64 + kk;
            s += __bfloat162float(z3l[ptq][k]) * fc4w[o * 256 + k];
        }
        s += __shfl_xor(s, 16);
        s += __shfl_xor(s, 32);
        if (kg == 0) {
            const int pg = p0 + ptq;
            if (pg < m) out[pg * 3 + o] = s + fc4b[o];
        }
    }
}

extern "C" void kernel_launch(void* const* d_in, const int* in_sizes, int n_in,
                              void* d_out, int out_size, void* d_ws, size_t ws_size,
                              hipStream_t stream) {
    const float* x      = (const float*)d_in[1];
    const float* v0     = (const float*)d_in[2];
    const float* v1     = (const float*)d_in[3];
    const float* v2     = (const float*)d_in[4];
    const float* v3     = (const float*)d_in[5];
    const float* conv_w = (const float*)d_in[6];
    const float* conv_b = (const float*)d_in[7];
    const float* lfc_w  = (const float*)d_in[8];
    const float* lfc_b  = (const float*)d_in[9];
    const float* fc1_w  = (const float*)d_in[10];
    const float* fc1_b  = (const float*)d_in[11];
    const float* fc2_w  = (const float*)d_in[12];
    const float* fc2_b  = (const float*)d_in[13];
    const float* fc3_w  = (const float*)d_in[14];
    const float* fc3_b  = (const float*)d_in[15];
    const float* fc4_w  = (const float*)d_in[16];
    const float* fc4_b  = (const float*)d_in[17];
    float* out = (float*)d_out;
    const int m = in_sizes[1] / 3;

    char* ws = (char*)d_ws;
    size_t woff = 0;
    __hip_bfloat16* w0f = (__hip_bfloat16*)(ws + woff); woff += (size_t)55296 * 2;
    __hip_bfloat16* w1f = (__hip_bfloat16*)(ws + woff); woff += (size_t)8192 * 2;
    __hip_bfloat16* w2f = (__hip_bfloat16*)(ws + woff); woff += (size_t)131072 * 2;
    __hip_bfloat16* w3f = (__hip_bfloat16*)(ws + woff); woff += (size_t)131072 * 2;
    woff = (woff + 255) & ~(size_t)255;
    float* vt = (float*)(ws + woff);
    const size_t need = woff + (size_t)4 * VOXELS * 32 * 4;
    const bool chlast = (ws_size >= need);

    k_prepw<<<(55296 + 255) / 256, 256, 0, stream>>>(conv_w, w0f, 64, 864, 1);
    k_prepw<<<(8192 + 255) / 256, 256, 0, stream>>>(lfc_w, w1f, 128, 64, 0);
    k_prepw<<<(131072 + 255) / 256, 256, 0, stream>>>(fc2_w, w2f, 512, 256, 0);
    k_prepw<<<(131072 + 255) / 256, 256, 0, stream>>>(fc3_w, w3f, 256, 512, 0);
    if (chlast) {
        k_transpose<<<16384, 256, 0, stream>>>(v0, v1, v2, v3, vt);
    }

    const int nb = (m + 15) / 16;
    if (chlast) {
        k_fused<true><<<nb, 1024, 0, stream>>>(x, vt, v0, v1, v2, v3,
                                               w0f, conv_b, w1f, lfc_b, fc1_w, fc1_b,
                                               w2f, fc2_b, w3f, fc3_b, fc4_w, fc4_b, out, m);
    } else {
        k_fused<false><<<nb, 1024, 0, stream>>>(x, vt, v0, v1, v2, v3,
                                                w0f, conv_b, w1f, lfc_b, fc1_w, fc1_b,
                                                w2f, fc2_b, w3f, fc3_b, fc4_w, fc4_b, out, m);
    }
}

// Round 3
// 680.194 us; speedup vs baseline: 1.5033x; 1.0662x over previous
//
#include <hip/hip_runtime.h>
#include <hip/hip_bf16.h>

typedef __attribute__((ext_vector_type(8))) short short8;
typedef __attribute__((ext_vector_type(4))) float f32x4;

#define VOXELS 262144  // 64^3
#define F_PAD  872     // 864 + 8 ; 1744 B row stride (16-mult, 2-way bank alias only)
#define ZC_PAD 264     // 256 + 8
#define Z0_PAD 72      // 64 + 8
#define Z2_PAD 520     // 512 + 8
#define Z3_PAD 264     // 256 + 8

// ---------------- volume transpose: (C,D,H,W) -> (D,H,W,C) fp32 ----------------
__global__ void k_transpose(const float* __restrict__ v0, const float* __restrict__ v1,
                            const float* __restrict__ v2, const float* __restrict__ v3,
                            float* __restrict__ vt) {
    int b  = blockIdx.x;
    int q  = b >> 12;          // 4096 (z,y) rows per volume
    int zy = b & 4095;
    const float* src = (q == 0) ? v0 : (q == 1) ? v1 : (q == 2) ? v2 : v3;
    __shared__ float buf[32][65];
    int t = threadIdx.x;
    int x = t & 63, c0 = t >> 6;               // 4 channels per pass
    for (int cp = 0; cp < 32; cp += 4) {
        int c = c0 + cp;
        buf[c][x] = src[(size_t)c * VOXELS + (size_t)zy * 64 + x];
    }
    __syncthreads();
    int c = t & 31, xg = t >> 5;
    float* dst = vt + ((size_t)q * VOXELS + (size_t)zy * 64) * 32;
    for (int xx = xg; xx < 64; xx += 8) {
        dst[xx * 32 + c] = buf[c][xx];
    }
}

// ------------- weight pack: W[O][K] fp32 -> bf16 MFMA-B fragment order -------------
// out[((otile*KSTEPS + kstep)*64 + lane)*8 + e] = W[otile*16 + (lane&15)][kstep*32 + (lane>>4)*8 + e]
// conv_remap: logical k = s*32+c maps to source index c*27+s (conv_w is [O][C2][27])
__global__ void k_prepw(const float* __restrict__ W, __hip_bfloat16* __restrict__ wf,
                        int O, int K, int conv_remap) {
    int n = blockIdx.x * blockDim.x + threadIdx.x;
    if (n >= O * K) return;
    int e = n & 7, lane = (n >> 3) & 63;
    int rest = n >> 9;
    int ksteps = K >> 5;
    int kstep = rest % ksteps, otile = rest / ksteps;
    int o = otile * 16 + (lane & 15);
    int k = kstep * 32 + (lane >> 4) * 8 + e;
    int ksrc = conv_remap ? ((k & 31) * 27 + (k >> 5)) : k;
    wf[n] = __float2bfloat16(W[(size_t)o * K + ksrc]);
}

// ---------------- fully fused: sample -> conv -> lfc -> fc1..fc4 ----------------
template <bool CHLAST>
__global__ __launch_bounds__(1024, 4)
void k_fused(const float* __restrict__ xin, const float* __restrict__ vt,
             const float* __restrict__ v0, const float* __restrict__ v1,
             const float* __restrict__ v2, const float* __restrict__ v3,
             const __hip_bfloat16* __restrict__ w0f, const float* __restrict__ b0,
             const __hip_bfloat16* __restrict__ w1f, const float* __restrict__ b1,
             const float* __restrict__ fc1w, const float* __restrict__ fc1b,
             const __hip_bfloat16* __restrict__ w2f, const float* __restrict__ b2,
             const __hip_bfloat16* __restrict__ w3f, const float* __restrict__ b3,
             const float* __restrict__ fc4w, const float* __restrict__ fc4b,
             float* __restrict__ out, int m) {
    __shared__ __align__(16) __hip_bfloat16 f_lds[16][F_PAD];
    __shared__ __align__(16) __hip_bfloat16 zcat[16][ZC_PAD];
    __shared__ __align__(16) __hip_bfloat16 z0l[16][Z0_PAD];
    __shared__ __align__(16) __hip_bfloat16 z2l[16][Z2_PAD];
    __shared__ __align__(16) __hip_bfloat16 z3l[16][Z3_PAD];
    __shared__ float ptl[16][3];

    const int tid  = threadIdx.x;
    const int wave = tid >> 6;
    const int lane = tid & 63;
    const int p0   = blockIdx.x * 16;

    // ================= phase 1: sampling (one wave per point) =================
    // Corner-per-lane layout: lane = 8 corners x 8 channel-groups.
    //   g  = lane&7   -> channels 4g..4g+3 (one float4 in channel-last layout)
    //   cx = bit3, cy = bit4, cz = bit5 -> trilinear corner
    // Per-axis offsets/weights are computed once per (q,pos) and PRE-SELECTED by
    // the lane's corner bit into statically-indexed register arrays, so each of
    // the 108 taps costs only 2 adds (addr) + 2 muls (weight) + 4 fma + 1 VMEM.
    // Corner sum via 3-level shfl_xor (LDS pipe, not VALU).
    {
        const int pt = wave;
        const int p  = min(p0 + pt, m - 1);
        const float px = xin[p * 3 + 0];
        const float py = xin[p * 3 + 1];
        const float pz = xin[p * 3 + 2];
        if (lane == 0) { ptl[pt][0] = px; ptl[pt][1] = py; ptl[pt][2] = pz; }

        const int g  = lane & 7;
        const int cx = (lane >> 3) & 1;
        const int cy = (lane >> 4) & 1;
        const int cz = (lane >> 5) & 1;

        // (p + g*sc + 1)*31.5 = (p*31.5 + 31.5) + g*(sc*31.5)
        const float pxs = px * 31.5f + 31.5f;
        const float pys = py * 31.5f + 31.5f;
        const float pzs = pz * 31.5f + 31.5f;

        // byte-offset shifts: channel-last idx = ((z*64+y)*64+x)*32ch*4B
        const int XS = CHLAST ? 7 : 2;    // x*128B  | x*4B
        const int YS = CHLAST ? 13 : 8;   // y*8192B | y*256B
        const int ZS = CHLAST ? 19 : 14;  // z*512KB | z*16KB

        int   xoS[4][3], yoS[4][3], zoS[4][3];
        float wxS[4][3], wyS[4][3], wzS[4][3];
#pragma unroll
        for (int q = 0; q < 4; ++q) {
            const float sc31 = (float)(2 << q) * (31.5f / 64.0f);
#pragma unroll
            for (int pos = 0; pos < 3; ++pos) {
                const float gv = (-2.0f + 1.5f * (float)pos) * sc31;  // compile-time
                {   // x axis
                    float ix = fminf(fmaxf(pxs + gv, 0.f), 63.f);
                    float xf = floorf(ix); int x0 = (int)xf; float fx = ix - xf;
                    int x1 = min(x0 + 1, 63);
                    xoS[q][pos] = ((cx ? x1 : x0) << XS) + (CHLAST ? g * 16 : 0);
                    wxS[q][pos] = cx ? fx : 1.f - fx;
                }
                {   // y axis
                    float iy = fminf(fmaxf(pys + gv, 0.f), 63.f);
                    float yf = floorf(iy); int y0 = (int)yf; float fy = iy - yf;
                    int y1 = min(y0 + 1, 63);
                    yoS[q][pos] = (cy ? y1 : y0) << YS;
                    wyS[q][pos] = cy ? fy : 1.f - fy;
                }
                {   // z axis
                    float iz = fminf(fmaxf(pzs + gv, 0.f), 63.f);
                    float zf = floorf(iz); int z0 = (int)zf; float fz = iz - zf;
                    int z1 = min(z0 + 1, 63);
                    zoS[q][pos] = ((cz ? z1 : z0) << ZS) + (CHLAST ? q * 33554432 : 0);
                    wzS[q][pos] = cz ? fz : 1.f - fz;
                }
            }
        }

        const char* __restrict__ vtb = (const char*)vt;
#pragma unroll
        for (int j = 0; j < 3; ++j)
#pragma unroll
        for (int i = 0; i < 3; ++i)
#pragma unroll
        for (int k = 0; k < 3; ++k) {
            f32x4 acc = {0.f, 0.f, 0.f, 0.f};
#pragma unroll
            for (int q = 0; q < 4; ++q) {
                const int addr = zoS[q][k] + yoS[q][i] + xoS[q][j];
                f32x4 v;
                if (CHLAST) {
                    v = *(const f32x4*)(vtb + addr);
                } else {
                    const char* vqb = (const char*)((q == 0) ? v0 : (q == 1) ? v1
                                                   : (q == 2) ? v2 : v3);
#pragma unroll
                    for (int e = 0; e < 4; ++e)
                        v[e] = *(const float*)(vqb + addr + (size_t)(g * 4 + e) * (VOXELS * 4));
                }
                const float w = wzS[q][k] * wyS[q][i] * wxS[q][j];
#pragma unroll
                for (int r = 0; r < 4; ++r) acc[r] += w * v[r];
            }
            // reduce over the 8 corner lanes (bits 3,4,5)
#pragma unroll
            for (int r = 0; r < 4; ++r) {
                acc[r] += __shfl_xor(acc[r], 8);
                acc[r] += __shfl_xor(acc[r], 16);
                acc[r] += __shfl_xor(acc[r], 32);
            }
            if (lane < 8) {
                const int col = (j * 9 + i * 3 + k) * 32 + lane * 4;
#pragma unroll
                for (int e = 0; e < 4; ++e)
                    f_lds[pt][col + e] = __float2bfloat16(acc[e]);
            }
        }
    }
    __syncthreads();

    // ============ phase 2a: z_point = leaky(x @ fc1^T + b) -> zcat[:,0:128] ============
    {
        const int ptp = tid >> 6;
        const int ob  = tid & 63;
        const float qx = ptl[ptp][0], qy = ptl[ptp][1], qz = ptl[ptp][2];
#pragma unroll
        for (int r = 0; r < 2; ++r) {
            const int o = ob + 64 * r;
            float v = qx * fc1w[o * 3 + 0] + qy * fc1w[o * 3 + 1] + qz * fc1w[o * 3 + 2] + fc1b[o];
            v = fmaxf(v, 0.2f * v);
            zcat[ptp][o] = __float2bfloat16(v);
        }
    }

    // ============ phase 2b: conv GEMM [16x864]x[864x64] (waves 0..3) ============
    if (wave < 4) {
        f32x4 acc = {0.f, 0.f, 0.f, 0.f};
        const int row = lane & 15, g = lane >> 4;
        for (int ks = 0; ks < 27; ++ks) {
            short8 af = *(const short8*)&f_lds[row][ks * 32 + g * 8];
            short8 bf = *(const short8*)(w0f + (((size_t)wave * 27 + ks) * 64 + lane) * 8);
            acc = __builtin_amdgcn_mfma_f32_16x16x32_bf16(af, bf, acc, 0, 0, 0);
        }
        const int o = wave * 16 + row;
        const float bias = b0[o];
#pragma unroll
        for (int r = 0; r < 4; ++r)
            z0l[g * 4 + r][o] = __float2bfloat16(acc[r] + bias);
    }
    __syncthreads();

    // ============ phase 3: lfc GEMM [16x64]x[64x128] (waves 0..7) -> zcat[:,128:256] ============
    if (wave < 8) {
        f32x4 acc = {0.f, 0.f, 0.f, 0.f};
        const int row = lane & 15, g = lane >> 4;
#pragma unroll
        for (int ks = 0; ks < 2; ++ks) {
            short8 af = *(const short8*)&z0l[row][ks * 32 + g * 8];
            short8 bf = *(const short8*)(w1f + (((size_t)wave * 2 + ks) * 64 + lane) * 8);
            acc = __builtin_amdgcn_mfma_f32_16x16x32_bf16(af, bf, acc, 0, 0, 0);
        }
        const int o = wave * 16 + row;
        const float bias = b1[o];
#pragma unroll
        for (int r = 0; r < 4; ++r)
            zcat[g * 4 + r][128 + o] = __float2bfloat16(acc[r] + bias);
    }
    __syncthreads();

    // ============ phase 4: fc2 [16x256]x[256x512], leaky (16 waves x 2 tiles) ============
    {
        const int row = lane & 15, g = lane >> 4;
#pragma unroll
        for (int rt = 0; rt < 2; ++rt) {
            const int tile = wave * 2 + rt;
            f32x4 acc = {0.f, 0.f, 0.f, 0.f};
#pragma unroll
            for (int ks = 0; ks < 8; ++ks) {
                short8 af = *(const short8*)&zcat[row][ks * 32 + g * 8];
                short8 bf = *(const short8*)(w2f + (((size_t)tile * 8 + ks) * 64 + lane) * 8);
                acc = __builtin_amdgcn_mfma_f32_16x16x32_bf16(af, bf, acc, 0, 0, 0);
            }
            const int o = tile * 16 + row;
            const float bias = b2[o];
#pragma unroll
            for (int r = 0; r < 4; ++r) {
                float v = acc[r] + bias;
                v = fmaxf(v, 0.2f * v);
                z2l[g * 4 + r][o] = __float2bfloat16(v);
            }
        }
    }
    __syncthreads();

    // ============ phase 5: fc3 [16x512]x[512x256], leaky (wave = tile) ============
    {
        const int row = lane & 15, g = lane >> 4;
        f32x4 acc = {0.f, 0.f, 0.f, 0.f};
        for (int ks = 0; ks < 16; ++ks) {
            short8 af = *(const short8*)&z2l[row][ks * 32 + g * 8];
            short8 bf = *(const short8*)(w3f + (((size_t)wave * 16 + ks) * 64 + lane) * 8);
            acc = __builtin_amdgcn_mfma_f32_16x16x32_bf16(af, bf, acc, 0, 0, 0);
        }
        const int o = wave * 16 + row;
        const float bias = b3[o];
#pragma unroll
        for (int r = 0; r < 4; ++r) {
            float v = acc[r] + bias;
            v = fmaxf(v, 0.2f * v);
            z3l[g * 4 + r][o] = __float2bfloat16(v);
        }
    }
    __syncthreads();

    // ============ phase 6: fc4 [16x256]x[256x3] (waves 0..2, o = wave) ============
    if (wave < 3) {
        const int ptq = lane & 15, kg = lane >> 4;
        const int o = wave;
        float s = 0.f;
        for (int kk = 0; kk < 64; ++kk) {
            const int k = kg * 64 + kk;
            s += __bfloat162float(z3l[ptq][k]) * fc4w[o * 256 + k];
        }
        s += __shfl_xor(s, 16);
        s += __shfl_xor(s, 32);
        if (kg == 0) {
            const int pg = p0 + ptq;
            if (pg < m) out[pg * 3 + o] = s + fc4b[o];
        }
    }
}

extern "C" void kernel_launch(void* const* d_in, const int* in_sizes, int n_in,
                              void* d_out, int out_size, void* d_ws, size_t ws_size,
                              hipStream_t stream) {
    const float* x      = (const float*)d_in[1];
    const float* v0     = (const float*)d_in[2];
    const float* v1     = (const float*)d_in[3];
    const float* v2     = (const float*)d_in[4];
    const float* v3     = (const float*)d_in[5];
    const float* conv_w = (const float*)d_in[6];
    const float* conv_b = (const float*)d_in[7];
    const float* lfc_w  = (const float*)d_in[8];
    const float* lfc_b  = (const float*)d_in[9];
    const float* fc1_w  = (const float*)d_in[10];
    const float* fc1_b  = (const float*)d_in[11];
    const float* fc2_w  = (const float*)d_in[12];
    const float* fc2_b  = (const float*)d_in[13];
    const float* fc3_w  = (const float*)d_in[14];
    const float* fc3_b  = (const float*)d_in[15];
    const float* fc4_w  = (const float*)d_in[16];
    const float* fc4_b  = (const float*)d_in[17];
    float* out = (float*)d_out;
    const int m = in_sizes[1] / 3;

    char* ws = (char*)d_ws;
    size_t woff = 0;
    __hip_bfloat16* w0f = (__hip_bfloat16*)(ws + woff); woff += (size_t)55296 * 2;
    __hip_bfloat16* w1f = (__hip_bfloat16*)(ws + woff); woff += (size_t)8192 * 2;
    __hip_bfloat16* w2f = (__hip_bfloat16*)(ws + woff); woff += (size_t)131072 * 2;
    __hip_bfloat16* w3f = (__hip_bfloat16*)(ws + woff); woff += (size_t)131072 * 2;
    woff = (woff + 255) & ~(size_t)255;
    float* vt = (float*)(ws + woff);
    const size_t need = woff + (size_t)4 * VOXELS * 32 * 4;
    const bool chlast = (ws_size >= need);

    k_prepw<<<(55296 + 255) / 256, 256, 0, stream>>>(conv_w, w0f, 64, 864, 1);
    k_prepw<<<(8192 + 255) / 256, 256, 0, stream>>>(lfc_w, w1f, 128, 64, 0);
    k_prepw<<<(131072 + 255) / 256, 256, 0, stream>>>(fc2_w, w2f, 512, 256, 0);
    k_prepw<<<(131072 + 255) / 256, 256, 0, stream>>>(fc3_w, w3f, 256, 512, 0);
    if (chlast) {
        k_transpose<<<16384, 256, 0, stream>>>(v0, v1, v2, v3, vt);
    }

    const int nb = (m + 15) / 16;
    if (chlast) {
        k_fused<true><<<nb, 1024, 0, stream>>>(x, vt, v0, v1, v2, v3,
                                               w0f, conv_b, w1f, lfc_b, fc1_w, fc1_b,
                                               w2f, fc2_b, w3f, fc3_b, fc4_w, fc4_b, out, m);
    } else {
        k_fused<false><<<nb, 1024, 0, stream>>>(x, vt, v0, v1, v2, v3,
                                                w0f, conv_b, w1f, lfc_b, fc1_w, fc1_b,
                                                w2f, fc2_b, w3f, fc3_b, fc4_w, fc4_b, out, m);
    }
}